// Round 8
// baseline (237.947 us; speedup 1.0000x reference)
//
#include <hip/hip_runtime.h>

// ---------------------------------------------------------------- constants
#define NI 20000          // items
#define NET 60001         // entity table rows (incl. padding row)
#define MASKED_ID 60000   // NUM_ENTITIES -> masked
#define NRT 25            // relation table rows
#define MASK_VAL -9000000000000000.0f

// workspace layout (float offsets)
#define OFF_RELDOT0 0
#define OFF_RELDOT1 32
#define OFF_IHB0   64
#define OFF_IHB1   (64 + 20000)
#define OFF_EDOT0  (64 + 40000)
#define OFF_EDOT1  (64 + 40000 + 60004)
#define OFF_G1     160128          // 16B-aligned; end of tables = 160072

// ---------------------------------------------------------------- kernel P
// (unchanged)
__global__ __launch_bounds__(256) void dots_kernel(
    const float* __restrict__ it0, const float* __restrict__ it1,
    const float* __restrict__ en0, const float* __restrict__ en1,
    const float* __restrict__ re0, const float* __restrict__ re1,
    const float* __restrict__ fcw, const float* __restrict__ fcb,
    float* __restrict__ ws)
{
    const float* tbl; const float* w; float* out; int n; float bm;
    switch (blockIdx.y) {
      case 0:  tbl = en0; w = fcw + 256; out = ws + OFF_EDOT0;   n = NET; bm = 0.f; break;
      case 1:  tbl = en1; w = fcw + 256; out = ws + OFF_EDOT1;   n = NET; bm = 0.f; break;
      case 2:  tbl = it0; w = fcw;       out = ws + OFF_IHB0;    n = NI;  bm = 1.f; break;
      case 3:  tbl = it1; w = fcw;       out = ws + OFF_IHB1;    n = NI;  bm = 1.f; break;
      case 4:  tbl = re0; w = fcw + 128; out = ws + OFF_RELDOT0; n = NRT; bm = 0.f; break;
      default: tbl = re1; w = fcw + 128; out = ws + OFF_RELDOT1; n = NRT; bm = 0.f; break;
    }
    const int tid = blockIdx.x * 256 + threadIdx.x;
    const int row = tid >> 3;
    const int sub = tid & 7;
    if (row >= n) return;
    const float4* trow = (const float4*)(tbl + (size_t)row * 128) + sub * 4;
    const float4* wv   = (const float4*)(w) + sub * 4;
    float d = 0.f;
    #pragma unroll
    for (int q = 0; q < 4; ++q) {
        float4 a = trow[q]; float4 b = wv[q];
        d += a.x * b.x + a.y * b.y + a.z * b.z + a.w * b.w;
    }
    d += __shfl_xor(d, 1);
    d += __shfl_xor(d, 2);
    d += __shfl_xor(d, 4);
    if (sub == 0) out[row] = d + bm * fcb[0];
}

// ---------------------------------------------------------------- kernel A v4
// R5 decomposition (one wave per (item,path), float2/lane) with FORCED MLP:
// 32 raw-asm global_load_dwordx2 into 32 live v2f outputs -> compiler cannot
// serialize/sink them (volatile, untracked). Logit phase fully drained BEFORE
// the asm loads so compiler-inserted vmcnt(N) (which counts only tracked loads
// but drains the HW counter) cannot over-drain our async loads. Softmax
// butterfly runs with all 32 loads in flight; one explicit vmcnt(0) +
// sched_barrier(0) (rule #18) before the FMA consume loop.
__global__ __launch_bounds__(256) void attn_kernel(
    const float2* __restrict__ it0, const float2* __restrict__ it1,
    const float2* __restrict__ en0, const float2* __restrict__ en1,
    const int* __restrict__ idx_e, const int* __restrict__ idx_r,
    const float* __restrict__ ws, float2* __restrict__ g0, float2* __restrict__ g1)
{
    const int p = blockIdx.y;
    const float2* ent  = p ? en1 : en0;
    const float2* itm  = p ? it1 : it0;
    const float* edot  = ws + (p ? OFF_EDOT1 : OFF_EDOT0);
    const float* ihb   = ws + (p ? OFF_IHB1  : OFF_IHB0);
    const float* rdot  = ws + (p ? OFF_RELDOT1 : OFF_RELDOT0);
    float2* g = p ? g1 : g0;

    const int lane = threadIdx.x & 63;
    const int n = blockIdx.x * 4 + (threadIdx.x >> 6);
    const int k = lane & 31;

    // ---- logit phase: compute e COMPLETELY (all its waitcnts drain here) ----
    const int ide = idx_e[n * 32 + k];
    const int idr = idx_r[n * 32 + k];
    float e = ihb[n] + rdot[idr] + edot[ide];
    e = e > 0.f ? e : 0.2f * e;                 // leaky relu, alpha=0.2
    if (ide == MASKED_ID) e = MASK_VAL;         // mask AFTER activation (matches ref)
    __builtin_amdgcn_sched_barrier(0);          // pin: no tracked-load waits below

    // ---- issue 32 async row loads (untracked raw asm; all stay in flight) ----
    typedef float v2f __attribute__((ext_vector_type(2)));
    v2f vb[32];
    const unsigned long long entb =
        (unsigned long long)(const void*)ent + (unsigned long long)lane * 8ull;
    #pragma unroll
    for (int kk = 0; kk < 32; ++kk) {
        const int id = __shfl(ide, kk);          // const lane -> v_readlane (SGPR)
        const unsigned long long a = entb + (unsigned long long)(unsigned)id * 512ull;
        asm volatile("global_load_dwordx2 %0, %1, off" : "=v"(vb[kk]) : "v"(a));
    }
    __builtin_amdgcn_sched_barrier(0);

    // ---- softmax butterfly (DS/VALU only; 32 loads still in flight) ----
    float m = e;
    #pragma unroll
    for (int msk = 1; msk < 32; msk <<= 1) m = fmaxf(m, __shfl_xor(m, msk));
    const float ex = __expf(e - m);
    float s = ex;
    #pragma unroll
    for (int msk = 1; msk < 32; msk <<= 1) s += __shfl_xor(s, msk);
    const float att = ex / s;

    // ---- drain, then consume ----
    asm volatile("s_waitcnt vmcnt(0)" ::: "memory");
    __builtin_amdgcn_sched_barrier(0);           // rule #18: FMAs must not hoist

    float hx = 0.f, hy = 0.f;
    #pragma unroll
    for (int kk = 0; kk < 32; ++kk) {
        const float a = __shfl(att, kk);         // const lane -> readlane (SGPR)
        hx = fmaf(a, vb[kk].x, hx);
        hy = fmaf(a, vb[kk].y, hy);
    }
    const float2 t = itm[n * 64 + lane];
    g[n * 64 + lane] = make_float2(hx + t.x, hy + t.y);
}

// ---------------------------------------------------------------- kernel B
// (unchanged; NOTE: g0 aliases d_out — safe, block-disjoint rows)
__global__ __launch_bounds__(256) void out_kernel(
    const float2* __restrict__ g0, const float2* __restrict__ g1,
    const float* __restrict__ W, const float* __restrict__ ob,
    float2* __restrict__ out)
{
    __shared__ float2 Ws[64][64];       // 32KB: one half of W
    __shared__ float  gs[2][16][128];   // 16KB

    const int tid = threadIdx.x;
    const int j   = tid & 63;
    const int wv  = tid >> 6;
    const int nb  = blockIdx.x * 16;

    {
        const float4* s0 = (const float4*)g0;
        const float4* s1 = (const float4*)g1;
        #pragma unroll
        for (int r = 0; r < 4; ++r) {
            const int q = r * 256 + tid;            // 0..1023
            const int path = q >> 9;
            const int it   = (q >> 5) & 15;
            const int c    = q & 31;
            const float4* src = path ? s1 : s0;
            ((float4*)gs)[q] = src[(nb + it) * 32 + c];
        }
    }

    float2 acc[2][4];
    #pragma unroll
    for (int pp = 0; pp < 2; ++pp)
        #pragma unroll
        for (int t = 0; t < 4; ++t) acc[pp][t] = make_float2(0.f, 0.f);

    const int ib = wv * 4;
    for (int half = 0; half < 2; ++half) {
        __syncthreads();
        const float2* Wsrc = (const float2*)(W + half * 64 * 128);
        #pragma unroll
        for (int r = 0; r < 16; ++r) {
            const int q = r * 256 + tid;             // 0..4095
            ((float2*)Ws)[q] = Wsrc[q];
        }
        __syncthreads();

        #pragma unroll 4
        for (int i4 = 0; i4 < 16; ++i4) {
            const int i = i4 * 4;
            const float2 w0 = Ws[i][j],   w1 = Ws[i+1][j];
            const float2 w2 = Ws[i+2][j], w3 = Ws[i+3][j];
            #pragma unroll
            for (int t = 0; t < 4; ++t) {
                const float4 a0 = *(const float4*)&gs[0][ib + t][half * 64 + i];
                const float4 a1 = *(const float4*)&gs[1][ib + t][half * 64 + i];
                acc[0][t].x = fmaf(a0.x, w0.x, acc[0][t].x);
                acc[0][t].x = fmaf(a0.y, w1.x, acc[0][t].x);
                acc[0][t].x = fmaf(a0.z, w2.x, acc[0][t].x);
                acc[0][t].x = fmaf(a0.w, w3.x, acc[0][t].x);
                acc[0][t].y = fmaf(a0.x, w0.y, acc[0][t].y);
                acc[0][t].y = fmaf(a0.y, w1.y, acc[0][t].y);
                acc[0][t].y = fmaf(a0.z, w2.y, acc[0][t].y);
                acc[0][t].y = fmaf(a0.w, w3.y, acc[0][t].y);
                acc[1][t].x = fmaf(a1.x, w0.x, acc[1][t].x);
                acc[1][t].x = fmaf(a1.y, w1.x, acc[1][t].x);
                acc[1][t].x = fmaf(a1.z, w2.x, acc[1][t].x);
                acc[1][t].x = fmaf(a1.w, w3.x, acc[1][t].x);
                acc[1][t].y = fmaf(a1.x, w0.y, acc[1][t].y);
                acc[1][t].y = fmaf(a1.y, w1.y, acc[1][t].y);
                acc[1][t].y = fmaf(a1.z, w2.y, acc[1][t].y);
                acc[1][t].y = fmaf(a1.w, w3.y, acc[1][t].y);
            }
        }
    }

    const float2 b = ((const float2*)ob)[j];
    #pragma unroll
    for (int t = 0; t < 4; ++t) {
        const int n = nb + ib + t;
        const float r0x = fmaxf(acc[0][t].x + b.x, 0.f);
        const float r0y = fmaxf(acc[0][t].y + b.y, 0.f);
        const float r1x = fmaxf(acc[1][t].x + b.x, 0.f);
        const float r1y = fmaxf(acc[1][t].y + b.y, 0.f);
        out[n * 64 + j] = make_float2(0.5f * (r0x + r1x), 0.5f * (r0y + r1y));
    }
}

// ---------------------------------------------------------------- launch
extern "C" void kernel_launch(void* const* d_in, const int* in_sizes, int n_in,
                              void* d_out, int out_size, void* d_ws, size_t ws_size,
                              hipStream_t stream)
{
    const float* it0 = (const float*)d_in[0];
    const float* it1 = (const float*)d_in[1];
    const float* en0 = (const float*)d_in[2];
    const float* en1 = (const float*)d_in[3];
    const float* re0 = (const float*)d_in[4];
    const float* re1 = (const float*)d_in[5];
    const float* fcw = (const float*)d_in[6];
    const float* fcb = (const float*)d_in[7];
    const float* ow  = (const float*)d_in[8];
    const float* obv = (const float*)d_in[9];
    const int* ie    = (const int*)d_in[10];
    const int* ir    = (const int*)d_in[11];

    float* ws  = (float*)d_ws;
    float* g0  = (float*)d_out;             // reuse d_out as g0 scratch (safe, see kernel B)
    float* g1  = ws + OFF_G1;

    dim3 gp((NET * 8 + 255) / 256, 6);
    hipLaunchKernelGGL(dots_kernel, gp, dim3(256), 0, stream,
                       it0, it1, en0, en1, re0, re1, fcw, fcb, ws);

    dim3 ga(NI / 4, 2);
    hipLaunchKernelGGL(attn_kernel, ga, dim3(256), 0, stream,
                       (const float2*)it0, (const float2*)it1,
                       (const float2*)en0, (const float2*)en1,
                       ie, ir, ws, (float2*)g0, (float2*)g1);

    hipLaunchKernelGGL(out_kernel, dim3(NI / 16), dim3(256), 0, stream,
                       (const float2*)g0, (const float2*)g1, ow, obv,
                       (float2*)d_out);
}

// Round 10
// 201.420 us; speedup vs baseline: 1.1813x; 1.1813x over previous
//
#include <hip/hip_runtime.h>

// ---------------------------------------------------------------- constants
#define NI 20000          // items
#define NET 60001         // entity table rows (incl. padding row)
#define MASKED_ID 60000   // NUM_ENTITIES -> masked
#define NRT 25            // relation table rows
#define MASK_VAL -9000000000000000.0f

// workspace layout (float offsets)
#define OFF_RELDOT0 0
#define OFF_RELDOT1 32
#define OFF_IHB0   64
#define OFF_IHB1   (64 + 20000)
#define OFF_EDOT0  (64 + 40000)
#define OFF_EDOT1  (64 + 40000 + 60004)
#define OFF_G1     160128                  // g1: 20000*128 f32 -> end 2,720,128
#define OFF_ENTB   2720256                 // bf16 table: 60004 rows * 128 uints
#define WS_NEED_BYTES ((size_t)(OFF_ENTB + (size_t)60004 * 128) * 4ull)

// pack two f32 -> 2x bf16 (RNE) in one uint
__device__ __forceinline__ unsigned pack_bf16x2(float x, float y) {
    unsigned bx = __builtin_bit_cast(unsigned, x);
    unsigned by = __builtin_bit_cast(unsigned, y);
    bx = bx + 0x7fffu + ((bx >> 16) & 1u);
    by = by + 0x7fffu + ((by >> 16) & 1u);
    return (bx >> 16) | (by & 0xffff0000u);
}

// ---------------------------------------------------------------- kernel P
// Precompute edot/ihb/reldot dots AND (cases 0/1) emit the packed interleaved
// bf16 payload table entB[id] = [path0 128xbf16 | path1 128xbf16] (512B/row).
__global__ __launch_bounds__(256) void dots_kernel(
    const float* __restrict__ it0, const float* __restrict__ it1,
    const float* __restrict__ en0, const float* __restrict__ en1,
    const float* __restrict__ re0, const float* __restrict__ re1,
    const float* __restrict__ fcw, const float* __restrict__ fcb,
    float* __restrict__ ws, int writeB)
{
    const float* tbl; const float* w; float* out; int n; float bm;
    switch (blockIdx.y) {
      case 0:  tbl = en0; w = fcw + 256; out = ws + OFF_EDOT0;   n = NET; bm = 0.f; break;
      case 1:  tbl = en1; w = fcw + 256; out = ws + OFF_EDOT1;   n = NET; bm = 0.f; break;
      case 2:  tbl = it0; w = fcw;       out = ws + OFF_IHB0;    n = NI;  bm = 1.f; break;
      case 3:  tbl = it1; w = fcw;       out = ws + OFF_IHB1;    n = NI;  bm = 1.f; break;
      case 4:  tbl = re0; w = fcw + 128; out = ws + OFF_RELDOT0; n = NRT; bm = 0.f; break;
      default: tbl = re1; w = fcw + 128; out = ws + OFF_RELDOT1; n = NRT; bm = 0.f; break;
    }
    const int tid = blockIdx.x * 256 + threadIdx.x;
    const int row = tid >> 3;
    const int sub = tid & 7;
    if (row >= n) return;
    const float4* trow = (const float4*)(tbl + (size_t)row * 128) + sub * 4;
    const float4* wv   = (const float4*)(w) + sub * 4;
    float4 a0 = trow[0], a1 = trow[1], a2 = trow[2], a3 = trow[3];
    float d = 0.f;
    {
        float4 b;
        b = wv[0]; d += a0.x*b.x + a0.y*b.y + a0.z*b.z + a0.w*b.w;
        b = wv[1]; d += a1.x*b.x + a1.y*b.y + a1.z*b.z + a1.w*b.w;
        b = wv[2]; d += a2.x*b.x + a2.y*b.y + a2.z*b.z + a2.w*b.w;
        b = wv[3]; d += a3.x*b.x + a3.y*b.y + a3.z*b.z + a3.w*b.w;
    }
    d += __shfl_xor(d, 1);   // stays within the aligned 8-lane group
    d += __shfl_xor(d, 2);
    d += __shfl_xor(d, 4);
    if (sub == 0) out[row] = d + bm * fcb[0];

    // emit bf16 payload (entity tables only)
    if (writeB && blockIdx.y < 2) {
        const int p = blockIdx.y;
        uint4* eb = (uint4*)((unsigned*)(ws + OFF_ENTB)
                             + (size_t)row * 128 + p * 64 + sub * 8);
        uint4 w0, w1;
        w0.x = pack_bf16x2(a0.x, a0.y); w0.y = pack_bf16x2(a0.z, a0.w);
        w0.z = pack_bf16x2(a1.x, a1.y); w0.w = pack_bf16x2(a1.z, a1.w);
        w1.x = pack_bf16x2(a2.x, a2.y); w1.y = pack_bf16x2(a2.z, a2.w);
        w1.z = pack_bf16x2(a3.x, a3.y); w1.w = pack_bf16x2(a3.z, a3.w);
        eb[0] = w0; eb[1] = w1;
    }
}

// ---------------------------------------------------------------- kernel A v5
// R5 decomposition (one wave per (item,path), dims {2*lane, 2*lane+1}).
// BF16=1: gather 256B bf16 half-rows (1 uint/lane) from entB -> half the bytes.
// BF16=0: fallback, gather 512B f32 rows (float2/lane) from en0/en1.
template<int BF16>
__global__ __launch_bounds__(256) void attn_kernel(
    const float2* __restrict__ it0, const float2* __restrict__ it1,
    const float2* __restrict__ en0, const float2* __restrict__ en1,
    const int* __restrict__ idx_e, const int* __restrict__ idx_r,
    const float* __restrict__ ws, float2* __restrict__ g0, float2* __restrict__ g1)
{
    const int p = blockIdx.y;
    const float2* ent  = p ? en1 : en0;
    const float2* itm  = p ? it1 : it0;
    const float* edot  = ws + (p ? OFF_EDOT1 : OFF_EDOT0);
    const float* ihb   = ws + (p ? OFF_IHB1  : OFF_IHB0);
    const float* rdot  = ws + (p ? OFF_RELDOT1 : OFF_RELDOT0);
    float2* g = p ? g1 : g0;

    const int lane = threadIdx.x & 63;
    const int n = blockIdx.x * 4 + (threadIdx.x >> 6);
    const int k = lane & 31;

    const int ide = idx_e[n * 32 + k];
    const int idr = idx_r[n * 32 + k];
    float e = ihb[n] + rdot[idr] + edot[ide];
    e = e > 0.f ? e : 0.2f * e;                 // leaky relu, alpha=0.2
    if (ide == MASKED_ID) e = MASK_VAL;         // mask AFTER activation (matches ref)

    // masked softmax over k=0..31 (butterfly; both 32-halves identical)
    float m = e;
    #pragma unroll
    for (int msk = 1; msk < 32; msk <<= 1) m = fmaxf(m, __shfl_xor(m, msk));
    const float ex = __expf(e - m);
    float s = ex;
    #pragma unroll
    for (int msk = 1; msk < 32; msk <<= 1) s += __shfl_xor(s, msk);
    const float att = ex / s;

    // weighted row gather
    float hx = 0.f, hy = 0.f;
    if (BF16) {
        const unsigned* entB = (const unsigned*)(ws + OFF_ENTB) + p * 64 + lane;
        #pragma unroll
        for (int kk = 0; kk < 32; ++kk) {
            const float a = __shfl(att, kk);
            const int  id = __shfl(ide, kk);
            const unsigned wbits = entB[(size_t)id * 128];   // 2x bf16, 256B/row coalesced
            const float vx = __builtin_bit_cast(float, wbits << 16);
            const float vy = __builtin_bit_cast(float, wbits & 0xffff0000u);
            hx = fmaf(a, vx, hx);
            hy = fmaf(a, vy, hy);
        }
    } else {
        #pragma unroll
        for (int kk = 0; kk < 32; ++kk) {
            const float a = __shfl(att, kk);
            const int  id = __shfl(ide, kk);
            const float2 v = ent[id * 64 + lane];            // 512B/row coalesced
            hx = fmaf(a, v.x, hx);
            hy = fmaf(a, v.y, hy);
        }
    }
    const float2 t = itm[n * 64 + lane];
    g[n * 64 + lane] = make_float2(hx + t.x, hy + t.y);
}

// ---------------------------------------------------------------- kernel B
// (unchanged; NOTE: g0 aliases d_out — safe, block-disjoint rows)
__global__ __launch_bounds__(256) void out_kernel(
    const float2* __restrict__ g0, const float2* __restrict__ g1,
    const float* __restrict__ W, const float* __restrict__ ob,
    float2* __restrict__ out)
{
    __shared__ float2 Ws[64][64];       // 32KB: one half of W
    __shared__ float  gs[2][16][128];   // 16KB

    const int tid = threadIdx.x;
    const int j   = tid & 63;
    const int wv  = tid >> 6;
    const int nb  = blockIdx.x * 16;

    {
        const float4* s0 = (const float4*)g0;
        const float4* s1 = (const float4*)g1;
        #pragma unroll
        for (int r = 0; r < 4; ++r) {
            const int q = r * 256 + tid;            // 0..1023
            const int path = q >> 9;
            const int it   = (q >> 5) & 15;
            const int c    = q & 31;
            const float4* src = path ? s1 : s0;
            ((float4*)gs)[q] = src[(nb + it) * 32 + c];
        }
    }

    float2 acc[2][4];
    #pragma unroll
    for (int pp = 0; pp < 2; ++pp)
        #pragma unroll
        for (int t = 0; t < 4; ++t) acc[pp][t] = make_float2(0.f, 0.f);

    const int ib = wv * 4;
    for (int half = 0; half < 2; ++half) {
        __syncthreads();
        const float2* Wsrc = (const float2*)(W + half * 64 * 128);
        #pragma unroll
        for (int r = 0; r < 16; ++r) {
            const int q = r * 256 + tid;             // 0..4095
            ((float2*)Ws)[q] = Wsrc[q];
        }
        __syncthreads();

        #pragma unroll 4
        for (int i4 = 0; i4 < 16; ++i4) {
            const int i = i4 * 4;
            const float2 w0 = Ws[i][j],   w1 = Ws[i+1][j];
            const float2 w2 = Ws[i+2][j], w3 = Ws[i+3][j];
            #pragma unroll
            for (int t = 0; t < 4; ++t) {
                const float4 a0 = *(const float4*)&gs[0][ib + t][half * 64 + i];
                const float4 a1 = *(const float4*)&gs[1][ib + t][half * 64 + i];
                acc[0][t].x = fmaf(a0.x, w0.x, acc[0][t].x);
                acc[0][t].x = fmaf(a0.y, w1.x, acc[0][t].x);
                acc[0][t].x = fmaf(a0.z, w2.x, acc[0][t].x);
                acc[0][t].x = fmaf(a0.w, w3.x, acc[0][t].x);
                acc[0][t].y = fmaf(a0.x, w0.y, acc[0][t].y);
                acc[0][t].y = fmaf(a0.y, w1.y, acc[0][t].y);
                acc[0][t].y = fmaf(a0.z, w2.y, acc[0][t].y);
                acc[0][t].y = fmaf(a0.w, w3.y, acc[0][t].y);
                acc[1][t].x = fmaf(a1.x, w0.x, acc[1][t].x);
                acc[1][t].x = fmaf(a1.y, w1.x, acc[1][t].x);
                acc[1][t].x = fmaf(a1.z, w2.x, acc[1][t].x);
                acc[1][t].x = fmaf(a1.w, w3.x, acc[1][t].x);
                acc[1][t].y = fmaf(a1.x, w0.y, acc[1][t].y);
                acc[1][t].y = fmaf(a1.y, w1.y, acc[1][t].y);
                acc[1][t].y = fmaf(a1.z, w2.y, acc[1][t].y);
                acc[1][t].y = fmaf(a1.w, w3.y, acc[1][t].y);
            }
        }
    }

    const float2 b = ((const float2*)ob)[j];
    #pragma unroll
    for (int t = 0; t < 4; ++t) {
        const int n = nb + ib + t;
        const float r0x = fmaxf(acc[0][t].x + b.x, 0.f);
        const float r0y = fmaxf(acc[0][t].y + b.y, 0.f);
        const float r1x = fmaxf(acc[1][t].x + b.x, 0.f);
        const float r1y = fmaxf(acc[1][t].y + b.y, 0.f);
        out[n * 64 + j] = make_float2(0.5f * (r0x + r1x), 0.5f * (r0y + r1y));
    }
}

// ---------------------------------------------------------------- launch
extern "C" void kernel_launch(void* const* d_in, const int* in_sizes, int n_in,
                              void* d_out, int out_size, void* d_ws, size_t ws_size,
                              hipStream_t stream)
{
    const float* it0 = (const float*)d_in[0];
    const float* it1 = (const float*)d_in[1];
    const float* en0 = (const float*)d_in[2];
    const float* en1 = (const float*)d_in[3];
    const float* re0 = (const float*)d_in[4];
    const float* re1 = (const float*)d_in[5];
    const float* fcw = (const float*)d_in[6];
    const float* fcb = (const float*)d_in[7];
    const float* ow  = (const float*)d_in[8];
    const float* obv = (const float*)d_in[9];
    const int* ie    = (const int*)d_in[10];
    const int* ir    = (const int*)d_in[11];

    float* ws  = (float*)d_ws;
    float* g0  = (float*)d_out;             // reuse d_out as g0 scratch (safe, see kernel B)
    float* g1  = ws + OFF_G1;

    const int useB = (ws_size >= WS_NEED_BYTES) ? 1 : 0;

    dim3 gp((NET * 8 + 255) / 256, 6);
    hipLaunchKernelGGL(dots_kernel, gp, dim3(256), 0, stream,
                       it0, it1, en0, en1, re0, re1, fcw, fcb, ws, useB);

    dim3 ga(NI / 4, 2);
    if (useB)
        hipLaunchKernelGGL((attn_kernel<1>), ga, dim3(256), 0, stream,
                           (const float2*)it0, (const float2*)it1,
                           (const float2*)en0, (const float2*)en1,
                           ie, ir, ws, (float2*)g0, (float2*)g1);
    else
        hipLaunchKernelGGL((attn_kernel<0>), ga, dim3(256), 0, stream,
                           (const float2*)it0, (const float2*)it1,
                           (const float2*)en0, (const float2*)en1,
                           ie, ir, ws, (float2*)g0, (float2*)g1);

    hipLaunchKernelGGL(out_kernel, dim3(NI / 16), dim3(256), 0, stream,
                       (const float2*)g0, (const float2*)g1, ow, obv,
                       (float2*)d_out);
}